// Round 4
// baseline (14184.132 us; speedup 1.0000x reference)
//
#include <hip/hip_runtime.h>

#define B_TOT 1024
#define L_T   100
#define DIN   32
#define HID   128
#define DOUT  32
#define BT    16      // batch rows per block (= MFMA M)
#define NBLK  64      // 1024 / 16
#define NTHREADS 1024 // 16 waves, 4 per SIMD -> VGPR must stay <= 128

typedef _Float16 half8 __attribute__((ext_vector_type(8)));
typedef float    f32x4 __attribute__((ext_vector_type(4)));

// XOR-swizzled index into a [16][128] f16 LDS tile (bank-conflict-free b128 reads)
#define SWZ(r,c) (((r) << 7) + ((c) ^ (((r) & 7) << 3)))

__device__ __forceinline__ float fast_exp2(float x){
#if __has_builtin(__builtin_amdgcn_exp2f)
  return __builtin_amdgcn_exp2f(x);
#else
  float r; asm("v_exp_f32 %0, %1\n\ts_nop 1" : "=v"(r) : "v"(x)); return r;
#endif
}
__device__ __forceinline__ float fast_rcp(float x){
#if __has_builtin(__builtin_amdgcn_rcpf)
  return __builtin_amdgcn_rcpf(x);
#else
  float r; asm("v_rcp_f32 %0, %1\n\ts_nop 1" : "=v"(r) : "v"(x)); return r;
#endif
}
__device__ __forceinline__ float fast_tanh(float x){
  float e = fast_exp2(x * 2.885390081777926f);  // 2*log2(e)
  return 1.0f - 2.0f * fast_rcp(e + 1.0f);
}

// Reorder [N][K] f32 row-major weights into fragment-ready f16 tiles:
// dst[((tile*(K/32)+k0)*64 + lane)*8 + ki], lane = (n&15) + 16*((k>>3)&3)
__global__ void reorder_w(const float* __restrict__ src, _Float16* __restrict__ dst,
                          int N, int K){
  int id = blockIdx.x * 256 + threadIdx.x;
  if (id >= N * K) return;
  int n = id / K, k = id - n * K;
  int tile = n >> 4, nl = n & 15;
  int kq = (k >> 3) & 3, k0 = k >> 5, ki = k & 7;
  int lane = nl + (kq << 4);
  int K32 = K >> 5;
  dst[(((tile * K32 + k0) << 6) + lane) * 8 + ki] = (_Float16)src[id];
}

__global__ __launch_bounds__(NTHREADS) void cde_main(
    const float* __restrict__ coeffs, const float* __restrict__ times,
    const float* __restrict__ init_b, const float* __restrict__ fb0,
    const float* __restrict__ fb1,    const float* __restrict__ fb2,
    const float* __restrict__ fbf,    const float* __restrict__ dec_b,
    const _Float16* __restrict__ W,   float* __restrict__ out)
{
  __shared__ _Float16 actZ[BT*HID];  // stage input z (f16, swizzled)
  __shared__ _Float16 actB[BT*HID];
  __shared__ _Float16 actC[BT*HID];
  __shared__ float zf[BT][HID];      // fp32 master z
  __shared__ float dzs[BT][HID];     // vf output
  __shared__ float kacc[BT][HID];    // RK4 k-accumulator
  __shared__ float dxs[BT][DIN];     // dX/dt for current interval
  __shared__ float fbfs[HID*DIN];    // fwf bias staged in LDS (16 KiB)

  const int tid  = threadIdx.x;
  const int lane = tid & 63;
  const int w    = tid >> 6;   // wave 0..15
  const int cl   = lane & 15;
  const int g    = lane >> 4;
  const int b0   = blockIdx.x * BT;

  const _Float16* W0 = W;
  const _Float16* W1 = W + 16384;
  const _Float16* W2 = W + 32768;
  const _Float16* Wf = W + 49152;   // fwf: 4096x128 -> 256 tiles
  const _Float16* Wi = W + 573440;  // init_w
  const _Float16* Wd = W + 577536;  // dec_w
  const _Float16* Wfw = Wf + w * 16 * 2048;  // this wave's 16 tiles (64 KiB)

  // lgkm-only barrier, two-sided compiler clobbers + sched_barrier pins
  // (rule #18 hardening). vmcnt deliberately NOT drained: all cross-wave
  // deps are LDS-only; global traffic is read-only weights + out stores
  // with no in-kernel reader.
  auto bar = [&]{
    __builtin_amdgcn_sched_barrier(0);
    asm volatile("s_waitcnt lgkmcnt(0)" ::: "memory");
    __builtin_amdgcn_s_barrier();
    __builtin_amdgcn_sched_barrier(0);
    asm volatile("" ::: "memory");
  };

  // 4-deep Wf tile prefetch ring (64 VGPR). Depth MUST divide 16:
  // invariant "tile u lives in slot u&3" then survives the 16->0 wrap
  // (u=12..15 prefetch tiles 0,1,2,3 into slots 0,1,2,3). The round-2/3
  // depth-3 ring violated this (16 % 3 != 0) -> permuted weight tiles.
  half8 bf[4][4];
#define LOAD_TILE(SL, IDX) {                                        \
    const _Float16* _p = Wfw + (IDX)*2048 + lane*8;                 \
    bf[SL][0] = *(const half8*)(_p);                                \
    bf[SL][1] = *(const half8*)(_p + 512);                          \
    bf[SL][2] = *(const half8*)(_p + 1024);                         \
    bf[SL][3] = *(const half8*)(_p + 1536); }

  // fbf biases -> LDS (once)
  for (int i = tid; i < HID*DIN; i += NTHREADS) fbfs[i] = fbf[i];
  // prime the ring (consumed in first biglayer, several barriers away)
  LOAD_TILE(0, 0) LOAD_TILE(1, 1) LOAD_TILE(2, 2) LOAD_TILE(3, 3)

  // ---- init: z0 = coeffs[:,0,:] @ init_w.T + init_b ----
  if (tid < BT*DIN){
    int r = tid >> 5, d = tid & 31;
    actC[SWZ(r, d)] = (_Float16)coeffs[(b0 + r)*(L_T*DIN) + d];
  }
  bar();
  if (w < 8){
    f32x4 acc = {0.f,0.f,0.f,0.f};
    half8 a = *(const half8*)(actC + SWZ(cl, 8*g));
    half8 b = *(const half8*)(Wi + (w*64 + lane)*8);
    acc = __builtin_amdgcn_mfma_f32_16x16x32_f16(a, b, acc, 0, 0, 0);
    float bn = init_b[w*16 + cl];
#pragma unroll
    for (int r = 0; r < 4; ++r){
      float v = acc[r] + bn;
      zf[4*g + r][w*16 + cl] = v;
      actZ[SWZ(4*g + r, w*16 + cl)] = (_Float16)v;
    }
  }
  bar();

#define DENSE(IN, OB, WV, BIAS) {                                          \
    f32x4 acc = {0.f,0.f,0.f,0.f};                                         \
    _Pragma("unroll")                                                      \
    for (int kq = 0; kq < 4; ++kq){                                        \
      half8 a = *(const half8*)((IN) + SWZ(cl, kq*32 + 8*g));              \
      acc = __builtin_amdgcn_mfma_f32_16x16x32_f16(a, WV[kq], acc, 0,0,0);}\
    float bn = (BIAS)[w*16 + cl];                                          \
    _Pragma("unroll")                                                      \
    for (int r = 0; r < 4; ++r)                                            \
      (OB)[SWZ(4*g + r, w*16 + cl)] = (_Float16)fast_tanh(acc[r] + bn); }

#define DECODER(TS) {                                                      \
    int dw = w - 14;                                                       \
    f32x4 acc = {0.f,0.f,0.f,0.f};                                         \
    _Pragma("unroll")                                                      \
    for (int kq = 0; kq < 4; ++kq){                                        \
      half8 a = *(const half8*)(actZ + SWZ(cl, kq*32 + 8*g));              \
      half8 b = *(const half8*)(Wd + ((dw*4 + kq)*64 + lane)*8);           \
      acc = __builtin_amdgcn_mfma_f32_16x16x32_f16(a, b, acc, 0,0,0);}     \
    float bn = dec_b[dw*16 + cl];                                          \
    _Pragma("unroll")                                                      \
    for (int r = 0; r < 4; ++r)                                            \
      out[(b0 + 4*g + r)*(L_T*DOUT) + (TS)*DOUT + dw*16 + cl] = acc[r] + bn; }

  float dxlo[4], dxhi[4];

  for (int t = 0; t < L_T - 1; ++t){
    // decoder(t) on waves 14/15: overlaps dxs setup + dense0 of this step.
    // Safe: its actZ ds_reads drain at this wave's bar() below, and actZ
    // is first rewritten at s=0's combine, 4 barriers later.
    if (w >= 14) DECODER(t)

    float dt = times[t+1] - times[t];
    if (tid < BT*DIN){
      int r = tid >> 5, d = tid & 31;
      const float* cp = coeffs + (b0 + r)*(L_T*DIN) + t*DIN + d;
      dxs[r][d] = (cp[DIN] - cp[0]) / dt;
    }
    bar();
#pragma unroll
    for (int r = 0; r < 4; ++r){
      dxlo[r] = dxs[4*g + r][cl];
      dxhi[r] = dxs[4*g + r][16 + cl];
    }

    for (int s = 0; s < 4; ++s){
      half8 wvX[4], wvY[4];
      if (w < 8){
#pragma unroll
        for (int j = 0; j < 4; ++j){
          wvX[j] = *(const half8*)(W0 + ((w*4 + j)*64 + lane)*8);
          wvY[j] = *(const half8*)(W1 + ((w*4 + j)*64 + lane)*8);
        }
        DENSE(actZ, actB, wvX, fb0)
        // reload wvX <- W2 behind dense1 (register WAR, SSA-safe)
#pragma unroll
        for (int j = 0; j < 4; ++j)
          wvX[j] = *(const half8*)(W2 + ((w*4 + j)*64 + lane)*8);
      }
      bar();
      if (w < 8) DENSE(actB, actC, wvY, fb1)
      bar();
      if (w < 8) DENSE(actC, actB, wvX, fb2)
      bar();

      // ---- biglayer: all 16 waves, 8 h-rows each, 4-deep rolling prefetch
      {
        half8 af[4];
#pragma unroll
        for (int kq = 0; kq < 4; ++kq)
          af[kq] = *(const half8*)(actB + SWZ(cl, kq*32 + 8*g));
#pragma unroll
        for (int hh = 0; hh < 8; ++hh){
          const int uA = 2*hh, uB = 2*hh + 1;
          const int sA = uA & 3, sB = uB & 3;
          const int nA = (uA + 4) & 15, nB = (uB + 4) & 15;
          f32x4 accA = {0.f,0.f,0.f,0.f}, accB = {0.f,0.f,0.f,0.f};
#pragma unroll
          for (int j = 0; j < 4; ++j)
            accA = __builtin_amdgcn_mfma_f32_16x16x32_f16(af[j], bf[sA][j], accA, 0,0,0);
          LOAD_TILE(sA, nA)   // wrap-consistent: tile u always in slot u&3
#pragma unroll
          for (int j = 0; j < 4; ++j)
            accB = __builtin_amdgcn_mfma_f32_16x16x32_f16(af[j], bf[sB][j], accB, 0,0,0);
          LOAD_TILE(sB, nB)
          float bnA = fbfs[(w*16 + uA)*16 + cl];
          float bnB = fbfs[(w*16 + uB)*16 + cl];
          float p[4];
#pragma unroll
          for (int r = 0; r < 4; ++r)
            p[r] = fast_tanh(accA[r] + bnA)*dxlo[r] + fast_tanh(accB[r] + bnB)*dxhi[r];
#pragma unroll
          for (int m = 1; m < 16; m <<= 1){
#pragma unroll
            for (int r = 0; r < 4; ++r) p[r] += __shfl_xor(p[r], m, 64);
          }
          if (cl == 0){
#pragma unroll
            for (int r = 0; r < 4; ++r) dzs[4*g + r][w*8 + hh] = p[r];
          }
        }
      }
      bar();

      // ---- RK4 combine (2048 elems, 2 per thread)
#pragma unroll
      for (int j = 0; j < 2; ++j){
        int e = tid + NTHREADS*j;
        int r = e >> 7, c = e & 127;
        float kv = dzs[r][c];
        float nin;
        if (s == 0){ kacc[r][c] = kv;            nin = zf[r][c] + 0.5f*dt*kv; }
        else if (s == 1){ kacc[r][c] += 2.0f*kv; nin = zf[r][c] + 0.5f*dt*kv; }
        else if (s == 2){ kacc[r][c] += 2.0f*kv; nin = zf[r][c] + dt*kv; }
        else {
          float zn = zf[r][c] + (dt * (1.0f/6.0f)) * (kacc[r][c] + kv);
          zf[r][c] = zn; nin = zn;
        }
        actZ[SWZ(r, c)] = (_Float16)nin;
      }
      bar();
    }
  }
  if (w >= 14) DECODER(L_T - 1)
}

extern "C" void kernel_launch(void* const* d_in, const int* in_sizes, int n_in,
                              void* d_out, int out_size, void* d_ws, size_t ws_size,
                              hipStream_t stream){
  const float* coeffs = (const float*)d_in[0];
  const float* times  = (const float*)d_in[1];
  const float* init_w = (const float*)d_in[2];
  const float* init_b = (const float*)d_in[3];
  const float* fw0    = (const float*)d_in[4];
  const float* fb0    = (const float*)d_in[5];
  const float* fw1    = (const float*)d_in[6];
  const float* fb1    = (const float*)d_in[7];
  const float* fw2    = (const float*)d_in[8];
  const float* fb2    = (const float*)d_in[9];
  const float* fwf    = (const float*)d_in[10];
  const float* fbf    = (const float*)d_in[11];
  const float* dec_w  = (const float*)d_in[12];
  const float* dec_b  = (const float*)d_in[13];
  _Float16* W = (_Float16*)d_ws;

  hipLaunchKernelGGL(reorder_w, dim3(64),   dim3(256), 0, stream, fw0, W,          128, 128);
  hipLaunchKernelGGL(reorder_w, dim3(64),   dim3(256), 0, stream, fw1, W + 16384,  128, 128);
  hipLaunchKernelGGL(reorder_w, dim3(64),   dim3(256), 0, stream, fw2, W + 32768,  128, 128);
  hipLaunchKernelGGL(reorder_w, dim3(2048), dim3(256), 0, stream, fwf, W + 49152,  4096, 128);
  hipLaunchKernelGGL(reorder_w, dim3(16),   dim3(256), 0, stream, init_w, W + 573440, 128, 32);
  hipLaunchKernelGGL(reorder_w, dim3(16),   dim3(256), 0, stream, dec_w,  W + 577536,  32, 128);

  hipLaunchKernelGGL(cde_main, dim3(NBLK), dim3(NTHREADS), 0, stream,
                     coeffs, times, init_b, fb0, fb1, fb2, fbf, dec_b,
                     W, (float*)d_out);
}

// Round 5
// 10361.140 us; speedup vs baseline: 1.3690x; 1.3690x over previous
//
#include <hip/hip_runtime.h>

#define B_TOT 1024
#define L_T   100
#define DIN   32
#define HID   128
#define DOUT  32
#define BT    16      // batch rows per block (= MFMA M)
#define NBLK  64      // 1024 / 16
#define NTHREADS 1024 // 16 waves = 4 waves/SIMD, 1 block/CU

typedef _Float16 half8 __attribute__((ext_vector_type(8)));
typedef float    f32x4 __attribute__((ext_vector_type(4)));

// XOR-swizzled index into a [16][128] f16 LDS tile (bank-conflict-free b128 reads)
#define SWZ(r,c) (((r) << 7) + ((c) ^ (((r) & 7) << 3)))

__device__ __forceinline__ float fast_exp2(float x){
#if __has_builtin(__builtin_amdgcn_exp2f)
  return __builtin_amdgcn_exp2f(x);
#else
  float r; asm("v_exp_f32 %0, %1\n\ts_nop 1" : "=v"(r) : "v"(x)); return r;
#endif
}
__device__ __forceinline__ float fast_rcp(float x){
#if __has_builtin(__builtin_amdgcn_rcpf)
  return __builtin_amdgcn_rcpf(x);
#else
  float r; asm("v_rcp_f32 %0, %1\n\ts_nop 1" : "=v"(r) : "v"(x)); return r;
#endif
}
__device__ __forceinline__ float fast_tanh(float x){
  float e = fast_exp2(x * 2.885390081777926f);  // 2*log2(e)
  return 1.0f - 2.0f * fast_rcp(e + 1.0f);
}

// Reorder [N][K] f32 row-major weights into fragment-ready f16 tiles:
// dst[((tile*(K/32)+k0)*64 + lane)*8 + ki], lane = (n&15) + 16*((k>>3)&3)
__global__ void reorder_w(const float* __restrict__ src, _Float16* __restrict__ dst,
                          int N, int K){
  int id = blockIdx.x * 256 + threadIdx.x;
  if (id >= N * K) return;
  int n = id / K, k = id - n * K;
  int tile = n >> 4, nl = n & 15;
  int kq = (k >> 3) & 3, k0 = k >> 5, ki = k & 7;
  int lane = nl + (kq << 4);
  int K32 = K >> 5;
  dst[(((tile * K32 + k0) << 6) + lane) * 8 + ki] = (_Float16)src[id];
}

// 2nd launch_bounds arg = min waves per EU: 4 -> VGPR cap 128, exactly one
// 16-wave block resident per CU. Round 4 omitted it; compiler clamped to
// 64 VGPR (2 blocks/CU) and spilled ~11 GB/dispatch to scratch.
__global__ __launch_bounds__(NTHREADS, 4) void cde_main(
    const float* __restrict__ coeffs, const float* __restrict__ times,
    const float* __restrict__ init_b, const float* __restrict__ fb0,
    const float* __restrict__ fb1,    const float* __restrict__ fb2,
    const float* __restrict__ fbf,    const float* __restrict__ dec_b,
    const _Float16* __restrict__ W,   float* __restrict__ out)
{
  __shared__ _Float16 actZ[BT*HID];  // stage input z (f16, swizzled)
  __shared__ _Float16 actB[BT*HID];
  __shared__ _Float16 actC[BT*HID];
  __shared__ float zf[BT][HID];      // fp32 master z
  __shared__ float dzs[BT][HID];     // vf output
  __shared__ float kacc[BT][HID];    // RK4 k-accumulator
  __shared__ float dxs[BT][DIN];     // dX/dt for current interval
  __shared__ float fbfs[HID*DIN];    // fwf bias staged in LDS (16 KiB)

  const int tid  = threadIdx.x;
  const int lane = tid & 63;
  const int w    = tid >> 6;   // wave 0..15
  const int cl   = lane & 15;
  const int g    = lane >> 4;
  const int b0   = blockIdx.x * BT;

  const _Float16* W0 = W;
  const _Float16* W1 = W + 16384;
  const _Float16* W2 = W + 32768;
  const _Float16* Wf = W + 49152;   // fwf: 4096x128 -> 256 tiles
  const _Float16* Wi = W + 573440;  // init_w
  const _Float16* Wd = W + 577536;  // dec_w
  const _Float16* Wfw = Wf + w * 16 * 2048;  // this wave's 16 tiles (64 KiB)

  // lgkm-only barrier, two-sided compiler clobbers + sched_barrier pins.
  // vmcnt deliberately NOT drained: all cross-wave deps are LDS-only.
  auto bar = [&]{
    __builtin_amdgcn_sched_barrier(0);
    asm volatile("s_waitcnt lgkmcnt(0)" ::: "memory");
    __builtin_amdgcn_s_barrier();
    __builtin_amdgcn_sched_barrier(0);
    asm volatile("" ::: "memory");
  };

  // 2-deep Wf tile prefetch ring (32 VGPR). Depth divides 16, so the
  // invariant "tile u lives in slot u&1" survives the 16->0 wrap.
  half8 bf[2][4];
#define LOAD_TILE(SL, IDX) {                                        \
    const _Float16* _p = Wfw + (IDX)*2048 + lane*8;                 \
    bf[SL][0] = *(const half8*)(_p);                                \
    bf[SL][1] = *(const half8*)(_p + 512);                          \
    bf[SL][2] = *(const half8*)(_p + 1024);                         \
    bf[SL][3] = *(const half8*)(_p + 1536); }

  // fbf biases -> LDS (once)
  for (int i = tid; i < HID*DIN; i += NTHREADS) fbfs[i] = fbf[i];
  // prime the ring (consumed in first biglayer, several barriers away)
  LOAD_TILE(0, 0) LOAD_TILE(1, 1)

  // ---- init: z0 = coeffs[:,0,:] @ init_w.T + init_b ----
  if (tid < BT*DIN){
    int r = tid >> 5, d = tid & 31;
    actC[SWZ(r, d)] = (_Float16)coeffs[(b0 + r)*(L_T*DIN) + d];
  }
  bar();
  if (w < 8){
    f32x4 acc = {0.f,0.f,0.f,0.f};
    half8 a = *(const half8*)(actC + SWZ(cl, 8*g));
    half8 b = *(const half8*)(Wi + (w*64 + lane)*8);
    acc = __builtin_amdgcn_mfma_f32_16x16x32_f16(a, b, acc, 0, 0, 0);
    float bn = init_b[w*16 + cl];
#pragma unroll
    for (int r = 0; r < 4; ++r){
      float v = acc[r] + bn;
      zf[4*g + r][w*16 + cl] = v;
      actZ[SWZ(4*g + r, w*16 + cl)] = (_Float16)v;
    }
  }
  bar();

// Dense HID->HID layer; B-fragments loaded inline from L2-resident weights
// (4 independent 16B loads/wave; TLP across 4 waves/SIMD hides latency).
#define DENSE(IN, OB, WT, BIAS) {                                          \
    f32x4 acc = {0.f,0.f,0.f,0.f};                                         \
    _Pragma("unroll")                                                      \
    for (int kq = 0; kq < 4; ++kq){                                        \
      half8 a = *(const half8*)((IN) + SWZ(cl, kq*32 + 8*g));              \
      half8 b = *(const half8*)((WT) + ((w*4 + kq)*64 + lane)*8);          \
      acc = __builtin_amdgcn_mfma_f32_16x16x32_f16(a, b, acc, 0,0,0);}     \
    float bn = (BIAS)[w*16 + cl];                                          \
    _Pragma("unroll")                                                      \
    for (int r = 0; r < 4; ++r)                                            \
      (OB)[SWZ(4*g + r, w*16 + cl)] = (_Float16)fast_tanh(acc[r] + bn); }

#define DECODER(TS) {                                                      \
    int dw = w - 14;                                                       \
    f32x4 acc = {0.f,0.f,0.f,0.f};                                         \
    _Pragma("unroll")                                                      \
    for (int kq = 0; kq < 4; ++kq){                                        \
      half8 a = *(const half8*)(actZ + SWZ(cl, kq*32 + 8*g));              \
      half8 b = *(const half8*)(Wd + ((dw*4 + kq)*64 + lane)*8);           \
      acc = __builtin_amdgcn_mfma_f32_16x16x32_f16(a, b, acc, 0,0,0);}     \
    float bn = dec_b[dw*16 + cl];                                          \
    _Pragma("unroll")                                                      \
    for (int r = 0; r < 4; ++r)                                            \
      out[(b0 + 4*g + r)*(L_T*DOUT) + (TS)*DOUT + dw*16 + cl] = acc[r] + bn; }

  float dxlo[4], dxhi[4];

  for (int t = 0; t < L_T - 1; ++t){
    // decoder(t) on waves 14/15: overlaps dxs setup + dense0 of this step.
    // Safe: its actZ ds_reads drain at this wave's bar() below, and actZ
    // is first rewritten at s=0's combine, 4 barriers later.
    if (w >= 14) DECODER(t)

    float dt = times[t+1] - times[t];
    if (tid < BT*DIN){
      int r = tid >> 5, d = tid & 31;
      const float* cp = coeffs + (b0 + r)*(L_T*DIN) + t*DIN + d;
      dxs[r][d] = (cp[DIN] - cp[0]) / dt;
    }
    bar();
#pragma unroll
    for (int r = 0; r < 4; ++r){
      dxlo[r] = dxs[4*g + r][cl];
      dxhi[r] = dxs[4*g + r][16 + cl];
    }

    for (int s = 0; s < 4; ++s){
      if (w < 8) DENSE(actZ, actB, W0, fb0)
      bar();
      if (w < 8) DENSE(actB, actC, W1, fb1)
      bar();
      if (w < 8) DENSE(actC, actB, W2, fb2)
      bar();

      // ---- biglayer: all 16 waves, 8 h-rows each, 2-deep rolling prefetch
      {
        half8 af[4];
#pragma unroll
        for (int kq = 0; kq < 4; ++kq)
          af[kq] = *(const half8*)(actB + SWZ(cl, kq*32 + 8*g));
#pragma unroll
        for (int hh = 0; hh < 8; ++hh){
          const int uA = 2*hh, uB = 2*hh + 1;
          const int nA = (uA + 2) & 15, nB = (uB + 2) & 15;
          f32x4 accA = {0.f,0.f,0.f,0.f}, accB = {0.f,0.f,0.f,0.f};
#pragma unroll
          for (int j = 0; j < 4; ++j)
            accA = __builtin_amdgcn_mfma_f32_16x16x32_f16(af[j], bf[0][j], accA, 0,0,0);
          LOAD_TILE(0, nA)   // wrap-consistent: tile u always in slot u&1
#pragma unroll
          for (int j = 0; j < 4; ++j)
            accB = __builtin_amdgcn_mfma_f32_16x16x32_f16(af[j], bf[1][j], accB, 0,0,0);
          LOAD_TILE(1, nB)
          float bnA = fbfs[(w*16 + uA)*16 + cl];
          float bnB = fbfs[(w*16 + uB)*16 + cl];
          float p[4];
#pragma unroll
          for (int r = 0; r < 4; ++r)
            p[r] = fast_tanh(accA[r] + bnA)*dxlo[r] + fast_tanh(accB[r] + bnB)*dxhi[r];
#pragma unroll
          for (int m = 1; m < 16; m <<= 1){
#pragma unroll
            for (int r = 0; r < 4; ++r) p[r] += __shfl_xor(p[r], m, 64);
          }
          if (cl == 0){
#pragma unroll
            for (int r = 0; r < 4; ++r) dzs[4*g + r][w*8 + hh] = p[r];
          }
        }
      }
      bar();

      // ---- RK4 combine (2048 elems, 2 per thread)
#pragma unroll
      for (int j = 0; j < 2; ++j){
        int e = tid + NTHREADS*j;
        int r = e >> 7, c = e & 127;
        float kv = dzs[r][c];
        float nin;
        if (s == 0){ kacc[r][c] = kv;            nin = zf[r][c] + 0.5f*dt*kv; }
        else if (s == 1){ kacc[r][c] += 2.0f*kv; nin = zf[r][c] + 0.5f*dt*kv; }
        else if (s == 2){ kacc[r][c] += 2.0f*kv; nin = zf[r][c] + dt*kv; }
        else {
          float zn = zf[r][c] + (dt * (1.0f/6.0f)) * (kacc[r][c] + kv);
          zf[r][c] = zn; nin = zn;
        }
        actZ[SWZ(r, c)] = (_Float16)nin;
      }
      bar();
    }
  }
  if (w >= 14) DECODER(L_T - 1)
}

extern "C" void kernel_launch(void* const* d_in, const int* in_sizes, int n_in,
                              void* d_out, int out_size, void* d_ws, size_t ws_size,
                              hipStream_t stream){
  const float* coeffs = (const float*)d_in[0];
  const float* times  = (const float*)d_in[1];
  const float* init_w = (const float*)d_in[2];
  const float* init_b = (const float*)d_in[3];
  const float* fw0    = (const float*)d_in[4];
  const float* fb0    = (const float*)d_in[5];
  const float* fw1    = (const float*)d_in[6];
  const float* fb1    = (const float*)d_in[7];
  const float* fw2    = (const float*)d_in[8];
  const float* fb2    = (const float*)d_in[9];
  const float* fwf    = (const float*)d_in[10];
  const float* fbf    = (const float*)d_in[11];
  const float* dec_w  = (const float*)d_in[12];
  const float* dec_b  = (const float*)d_in[13];
  _Float16* W = (_Float16*)d_ws;

  hipLaunchKernelGGL(reorder_w, dim3(64),   dim3(256), 0, stream, fw0, W,          128, 128);
  hipLaunchKernelGGL(reorder_w, dim3(64),   dim3(256), 0, stream, fw1, W + 16384,  128, 128);
  hipLaunchKernelGGL(reorder_w, dim3(64),   dim3(256), 0, stream, fw2, W + 32768,  128, 128);
  hipLaunchKernelGGL(reorder_w, dim3(2048), dim3(256), 0, stream, fwf, W + 49152,  4096, 128);
  hipLaunchKernelGGL(reorder_w, dim3(16),   dim3(256), 0, stream, init_w, W + 573440, 128, 32);
  hipLaunchKernelGGL(reorder_w, dim3(16),   dim3(256), 0, stream, dec_w,  W + 577536,  32, 128);

  hipLaunchKernelGGL(cde_main, dim3(NBLK), dim3(NTHREADS), 0, stream,
                     coeffs, times, init_b, fb0, fb1, fb2, fbf, dec_b,
                     W, (float*)d_out);
}

// Round 6
// 10292.867 us; speedup vs baseline: 1.3781x; 1.0066x over previous
//
#include <hip/hip_runtime.h>

#define B_TOT 1024
#define L_T   100
#define DIN   32
#define HID   128
#define DOUT  32
#define BT    16      // batch rows per block (= MFMA M)
#define NBLK  64      // 1024 / 16
#define NTHREADS 1024 // 16 waves = 4 waves/SIMD, 1 block/CU

typedef _Float16 half8 __attribute__((ext_vector_type(8)));
typedef float    f32x4 __attribute__((ext_vector_type(4)));

// XOR-swizzled index into a [16][128] f16 LDS tile (bank-conflict-free b128 reads)
#define SWZ(r,c) (((r) << 7) + ((c) ^ (((r) & 7) << 3)))

__device__ __forceinline__ float fast_exp2(float x){
#if __has_builtin(__builtin_amdgcn_exp2f)
  return __builtin_amdgcn_exp2f(x);
#else
  float r; asm("v_exp_f32 %0, %1\n\ts_nop 1" : "=v"(r) : "v"(x)); return r;
#endif
}
__device__ __forceinline__ float fast_rcp(float x){
#if __has_builtin(__builtin_amdgcn_rcpf)
  return __builtin_amdgcn_rcpf(x);
#else
  float r; asm("v_rcp_f32 %0, %1\n\ts_nop 1" : "=v"(r) : "v"(x)); return r;
#endif
}
__device__ __forceinline__ float fast_tanh(float x){
  float e = fast_exp2(x * 2.885390081777926f);  // 2*log2(e)
  return 1.0f - 2.0f * fast_rcp(e + 1.0f);
}

// Reorder [N][K] f32 row-major weights into fragment-ready f16 tiles:
// dst[((tile*(K/32)+k0)*64 + lane)*8 + ki], lane = (n&15) + 16*((k>>3)&3)
__global__ void reorder_w(const float* __restrict__ src, _Float16* __restrict__ dst,
                          int N, int K){
  int id = blockIdx.x * 256 + threadIdx.x;
  if (id >= N * K) return;
  int n = id / K, k = id - n * K;
  int tile = n >> 4, nl = n & 15;
  int kq = (k >> 3) & 3, k0 = k >> 5, ki = k & 7;
  int lane = nl + (kq << 4);
  int K32 = K >> 5;
  dst[(((tile * K32 + k0) << 6) + lane) * 8 + ki] = (_Float16)src[id];
}

// amdgpu_waves_per_eu(4,4): PIN the occupancy target to exactly 4 waves/EU
// (= one 16-wave block/CU) -> VGPR budget 128. launch_bounds' 2nd arg alone
// only sets the range MINIMUM; the backend's LDS-driven heuristic (55 KiB ->
// 2 blocks/CU -> 8 waves/EU) still clamped to 64 VGPR and spilled ~4 GB
// (round 5: FETCH 3.7 GB, WRITE 120 MB, dur = spill-BW time).
__global__ __launch_bounds__(NTHREADS)
__attribute__((amdgpu_waves_per_eu(4, 4)))
void cde_main(
    const float* __restrict__ coeffs, const float* __restrict__ times,
    const float* __restrict__ init_b, const float* __restrict__ fb0,
    const float* __restrict__ fb1,    const float* __restrict__ fb2,
    const float* __restrict__ fbf,    const float* __restrict__ dec_b,
    const _Float16* __restrict__ W,   float* __restrict__ out)
{
  __shared__ _Float16 actZ[BT*HID];  // stage input z (f16, swizzled)
  __shared__ _Float16 actB[BT*HID];
  __shared__ _Float16 actC[BT*HID];
  __shared__ float zf[BT][HID];      // fp32 master z
  __shared__ float dzs[BT][HID];     // vf output
  __shared__ float kacc[BT][HID];    // RK4 k-accumulator
  __shared__ float dxs[BT][DIN];     // dX/dt for current interval
  __shared__ float fbfs[HID*DIN];    // fwf bias staged in LDS (16 KiB)

  const int tid  = threadIdx.x;
  const int lane = tid & 63;
  const int w    = tid >> 6;   // wave 0..15
  const int cl   = lane & 15;
  const int g    = lane >> 4;
  const int b0   = blockIdx.x * BT;

  const _Float16* W0 = W;
  const _Float16* W1 = W + 16384;
  const _Float16* W2 = W + 32768;
  const _Float16* Wf = W + 49152;   // fwf: 4096x128 -> 256 tiles
  const _Float16* Wi = W + 573440;  // init_w
  const _Float16* Wd = W + 577536;  // dec_w
  const _Float16* Wfw = Wf + w * 16 * 2048;  // this wave's 16 tiles (64 KiB)

  // lgkm-only barrier, two-sided compiler clobbers + sched_barrier pins.
  // vmcnt deliberately NOT drained: all cross-wave deps are LDS-only.
  auto bar = [&]{
    __builtin_amdgcn_sched_barrier(0);
    asm volatile("s_waitcnt lgkmcnt(0)" ::: "memory");
    __builtin_amdgcn_s_barrier();
    __builtin_amdgcn_sched_barrier(0);
    asm volatile("" ::: "memory");
  };

  // 2-deep Wf tile prefetch ring (32 VGPR). Depth divides 16, so the
  // invariant "tile u lives in slot u&1" survives the 16->0 wrap.
  half8 bf[2][4];
#define LOAD_TILE(SL, IDX) {                                        \
    const _Float16* _p = Wfw + (IDX)*2048 + lane*8;                 \
    bf[SL][0] = *(const half8*)(_p);                                \
    bf[SL][1] = *(const half8*)(_p + 512);                          \
    bf[SL][2] = *(const half8*)(_p + 1024);                         \
    bf[SL][3] = *(const half8*)(_p + 1536); }

  // fbf biases -> LDS (once)
  for (int i = tid; i < HID*DIN; i += NTHREADS) fbfs[i] = fbf[i];
  // prime the ring (consumed in first biglayer, several barriers away)
  LOAD_TILE(0, 0) LOAD_TILE(1, 1)

  // ---- init: z0 = coeffs[:,0,:] @ init_w.T + init_b ----
  if (tid < BT*DIN){
    int r = tid >> 5, d = tid & 31;
    actC[SWZ(r, d)] = (_Float16)coeffs[(b0 + r)*(L_T*DIN) + d];
  }
  bar();
  if (w < 8){
    f32x4 acc = {0.f,0.f,0.f,0.f};
    half8 a = *(const half8*)(actC + SWZ(cl, 8*g));
    half8 b = *(const half8*)(Wi + (w*64 + lane)*8);
    acc = __builtin_amdgcn_mfma_f32_16x16x32_f16(a, b, acc, 0, 0, 0);
    float bn = init_b[w*16 + cl];
#pragma unroll
    for (int r = 0; r < 4; ++r){
      float v = acc[r] + bn;
      zf[4*g + r][w*16 + cl] = v;
      actZ[SWZ(4*g + r, w*16 + cl)] = (_Float16)v;
    }
  }
  bar();

// Dense HID->HID layer; B-fragments loaded inline from L2-resident weights
// (4 independent 16B loads/wave; TLP across 4 waves/SIMD hides latency).
#define DENSE(IN, OB, WT, BIAS) {                                          \
    f32x4 acc = {0.f,0.f,0.f,0.f};                                         \
    _Pragma("unroll")                                                      \
    for (int kq = 0; kq < 4; ++kq){                                        \
      half8 a = *(const half8*)((IN) + SWZ(cl, kq*32 + 8*g));              \
      half8 b = *(const half8*)((WT) + ((w*4 + kq)*64 + lane)*8);          \
      acc = __builtin_amdgcn_mfma_f32_16x16x32_f16(a, b, acc, 0,0,0);}     \
    float bn = (BIAS)[w*16 + cl];                                          \
    _Pragma("unroll")                                                      \
    for (int r = 0; r < 4; ++r)                                            \
      (OB)[SWZ(4*g + r, w*16 + cl)] = (_Float16)fast_tanh(acc[r] + bn); }

#define DECODER(TS) {                                                      \
    int dw = w - 14;                                                       \
    f32x4 acc = {0.f,0.f,0.f,0.f};                                         \
    _Pragma("unroll")                                                      \
    for (int kq = 0; kq < 4; ++kq){                                        \
      half8 a = *(const half8*)(actZ + SWZ(cl, kq*32 + 8*g));              \
      half8 b = *(const half8*)(Wd + ((dw*4 + kq)*64 + lane)*8);           \
      acc = __builtin_amdgcn_mfma_f32_16x16x32_f16(a, b, acc, 0,0,0);}     \
    float bn = dec_b[dw*16 + cl];                                          \
    _Pragma("unroll")                                                      \
    for (int r = 0; r < 4; ++r)                                            \
      out[(b0 + 4*g + r)*(L_T*DOUT) + (TS)*DOUT + dw*16 + cl] = acc[r] + bn; }

  float dxlo[4], dxhi[4];

  for (int t = 0; t < L_T - 1; ++t){
    // decoder(t) on waves 14/15: overlaps dxs setup + dense0 of this step.
    // Safe: its actZ ds_reads drain at this wave's bar() below, and actZ
    // is first rewritten at s=0's combine, 4 barriers later.
    if (w >= 14) DECODER(t)

    float dt = times[t+1] - times[t];
    if (tid < BT*DIN){
      int r = tid >> 5, d = tid & 31;
      const float* cp = coeffs + (b0 + r)*(L_T*DIN) + t*DIN + d;
      dxs[r][d] = (cp[DIN] - cp[0]) / dt;
    }
    bar();
#pragma unroll
    for (int r = 0; r < 4; ++r){
      dxlo[r] = dxs[4*g + r][cl];
      dxhi[r] = dxs[4*g + r][16 + cl];
    }

    for (int s = 0; s < 4; ++s){
      if (w < 8) DENSE(actZ, actB, W0, fb0)
      bar();
      if (w < 8) DENSE(actB, actC, W1, fb1)
      bar();
      if (w < 8) DENSE(actC, actB, W2, fb2)
      bar();

      // ---- biglayer: all 16 waves, 8 h-rows each, 2-deep rolling prefetch
      {
        half8 af[4];
#pragma unroll
        for (int kq = 0; kq < 4; ++kq)
          af[kq] = *(const half8*)(actB + SWZ(cl, kq*32 + 8*g));
#pragma unroll
        for (int hh = 0; hh < 8; ++hh){
          const int uA = 2*hh, uB = 2*hh + 1;
          const int nA = (uA + 2) & 15, nB = (uB + 2) & 15;
          f32x4 accA = {0.f,0.f,0.f,0.f}, accB = {0.f,0.f,0.f,0.f};
#pragma unroll
          for (int j = 0; j < 4; ++j)
            accA = __builtin_amdgcn_mfma_f32_16x16x32_f16(af[j], bf[0][j], accA, 0,0,0);
          LOAD_TILE(0, nA)   // wrap-consistent: tile u always in slot u&1
#pragma unroll
          for (int j = 0; j < 4; ++j)
            accB = __builtin_amdgcn_mfma_f32_16x16x32_f16(af[j], bf[1][j], accB, 0,0,0);
          LOAD_TILE(1, nB)
          float bnA = fbfs[(w*16 + uA)*16 + cl];
          float bnB = fbfs[(w*16 + uB)*16 + cl];
          float p[4];
#pragma unroll
          for (int r = 0; r < 4; ++r)
            p[r] = fast_tanh(accA[r] + bnA)*dxlo[r] + fast_tanh(accB[r] + bnB)*dxhi[r];
#pragma unroll
          for (int m = 1; m < 16; m <<= 1){
#pragma unroll
            for (int r = 0; r < 4; ++r) p[r] += __shfl_xor(p[r], m, 64);
          }
          if (cl == 0){
#pragma unroll
            for (int r = 0; r < 4; ++r) dzs[4*g + r][w*8 + hh] = p[r];
          }
        }
      }
      bar();

      // ---- RK4 combine (2048 elems, 2 per thread)
#pragma unroll
      for (int j = 0; j < 2; ++j){
        int e = tid + NTHREADS*j;
        int r = e >> 7, c = e & 127;
        float kv = dzs[r][c];
        float nin;
        if (s == 0){ kacc[r][c] = kv;            nin = zf[r][c] + 0.5f*dt*kv; }
        else if (s == 1){ kacc[r][c] += 2.0f*kv; nin = zf[r][c] + 0.5f*dt*kv; }
        else if (s == 2){ kacc[r][c] += 2.0f*kv; nin = zf[r][c] + dt*kv; }
        else {
          float zn = zf[r][c] + (dt * (1.0f/6.0f)) * (kacc[r][c] + kv);
          zf[r][c] = zn; nin = zn;
        }
        actZ[SWZ(r, c)] = (_Float16)nin;
      }
      bar();
    }
  }
  if (w >= 14) DECODER(L_T - 1)
}

extern "C" void kernel_launch(void* const* d_in, const int* in_sizes, int n_in,
                              void* d_out, int out_size, void* d_ws, size_t ws_size,
                              hipStream_t stream){
  const float* coeffs = (const float*)d_in[0];
  const float* times  = (const float*)d_in[1];
  const float* init_w = (const float*)d_in[2];
  const float* init_b = (const float*)d_in[3];
  const float* fw0    = (const float*)d_in[4];
  const float* fb0    = (const float*)d_in[5];
  const float* fw1    = (const float*)d_in[6];
  const float* fb1    = (const float*)d_in[7];
  const float* fw2    = (const float*)d_in[8];
  const float* fb2    = (const float*)d_in[9];
  const float* fwf    = (const float*)d_in[10];
  const float* fbf    = (const float*)d_in[11];
  const float* dec_w  = (const float*)d_in[12];
  const float* dec_b  = (const float*)d_in[13];
  _Float16* W = (_Float16*)d_ws;

  hipLaunchKernelGGL(reorder_w, dim3(64),   dim3(256), 0, stream, fw0, W,          128, 128);
  hipLaunchKernelGGL(reorder_w, dim3(64),   dim3(256), 0, stream, fw1, W + 16384,  128, 128);
  hipLaunchKernelGGL(reorder_w, dim3(64),   dim3(256), 0, stream, fw2, W + 32768,  128, 128);
  hipLaunchKernelGGL(reorder_w, dim3(2048), dim3(256), 0, stream, fwf, W + 49152,  4096, 128);
  hipLaunchKernelGGL(reorder_w, dim3(16),   dim3(256), 0, stream, init_w, W + 573440, 128, 32);
  hipLaunchKernelGGL(reorder_w, dim3(16),   dim3(256), 0, stream, dec_w,  W + 577536,  32, 128);

  hipLaunchKernelGGL(cde_main, dim3(NBLK), dim3(NTHREADS), 0, stream,
                     coeffs, times, init_b, fb0, fb1, fb2, fbf, dec_b,
                     W, (float*)d_out);
}

// Round 7
// 5444.271 us; speedup vs baseline: 2.6053x; 1.8906x over previous
//
#include <hip/hip_runtime.h>

#define B_TOT 1024
#define L_T   100
#define DIN   32
#define HID   128
#define DOUT  32
#define BT    16      // batch rows per block (= MFMA M)
#define NBLK  64      // 1024 / 16
#define NTHREADS 1024 // 16 waves; 64-VGPR budget -> kernel dieted to fit

typedef _Float16 half8 __attribute__((ext_vector_type(8)));
typedef float    f32x4 __attribute__((ext_vector_type(4)));

// XOR-swizzled index into a [16][128] f16 LDS tile (bank-conflict-free b128 reads)
#define SWZ(r,c) (((r) << 7) + ((c) ^ (((r) & 7) << 3)))

__device__ __forceinline__ float fast_exp2(float x){
#if __has_builtin(__builtin_amdgcn_exp2f)
  return __builtin_amdgcn_exp2f(x);
#else
  float r; asm("v_exp_f32 %0, %1\n\ts_nop 1" : "=v"(r) : "v"(x)); return r;
#endif
}
__device__ __forceinline__ float fast_rcp(float x){
#if __has_builtin(__builtin_amdgcn_rcpf)
  return __builtin_amdgcn_rcpf(x);
#else
  float r; asm("v_rcp_f32 %0, %1\n\ts_nop 1" : "=v"(r) : "v"(x)); return r;
#endif
}
__device__ __forceinline__ float fast_tanh(float x){
  float e = fast_exp2(x * 2.885390081777926f);  // 2*log2(e)
  return 1.0f - 2.0f * fast_rcp(e + 1.0f);
}

// Reorder [N][K] f32 row-major weights into fragment-ready f16 tiles:
// dst[((tile*(K/32)+k0)*64 + lane)*8 + ki], lane = (n&15) + 16*((k>>3)&3)
__global__ void reorder_w(const float* __restrict__ src, _Float16* __restrict__ dst,
                          int N, int K){
  int id = blockIdx.x * 256 + threadIdx.x;
  if (id >= N * K) return;
  int n = id / K, k = id - n * K;
  int tile = n >> 4, nl = n & 15;
  int kq = (k >> 3) & 3, k0 = k >> 5, ki = k & 7;
  int lane = nl + (kq << 4);
  int K32 = K >> 5;
  dst[(((tile * K32 + k0) << 6) + lane) * 8 + ki] = (_Float16)src[id];
}

// Register budget reality (rounds 4-6): with 1024-thread workgroups the
// backend allocates for 8 waves/EU = 64 VGPR regardless of launch_bounds
// min-waves or amdgpu_waves_per_eu(4,4). So the kernel is structured to
// FIT 64 VGPR: no prefetch ring, one tile buffer, p-accumulation.
// 8 waves/EU TLP provides the latency hiding the ring was for.
__global__ __launch_bounds__(NTHREADS) void cde_main(
    const float* __restrict__ coeffs, const float* __restrict__ times,
    const float* __restrict__ init_b, const float* __restrict__ fb0,
    const float* __restrict__ fb1,    const float* __restrict__ fb2,
    const float* __restrict__ fbf,    const float* __restrict__ dec_b,
    const _Float16* __restrict__ W,   float* __restrict__ out)
{
  __shared__ _Float16 actZ[BT*HID];  // stage input z (f16, swizzled)
  __shared__ _Float16 actB[BT*HID];
  __shared__ _Float16 actC[BT*HID];
  __shared__ float zf[BT][HID];      // fp32 master z
  __shared__ float dzs[BT][HID];     // vf output
  __shared__ float kacc[BT][HID];    // RK4 k-accumulator
  __shared__ float dxs[BT][DIN];     // dX/dt for current interval
  __shared__ float fbfs[HID*DIN];    // fwf bias staged in LDS (16 KiB)

  const int tid  = threadIdx.x;
  const int lane = tid & 63;
  const int w    = tid >> 6;   // wave 0..15
  const int cl   = lane & 15;
  const int g    = lane >> 4;
  const int b0   = blockIdx.x * BT;

  const _Float16* W0 = W;
  const _Float16* W1 = W + 16384;
  const _Float16* W2 = W + 32768;
  const _Float16* Wf = W + 49152;   // fwf: 4096x128 -> 256 tiles
  const _Float16* Wi = W + 573440;  // init_w
  const _Float16* Wd = W + 577536;  // dec_w
  const _Float16* Wfw = Wf + w * 16 * 2048;  // this wave's 16 tiles (64 KiB)

  // lgkm-only barrier, two-sided compiler clobbers + sched_barrier pins.
  // vmcnt deliberately NOT drained: all cross-wave deps are LDS-only.
  auto bar = [&]{
    __builtin_amdgcn_sched_barrier(0);
    asm volatile("s_waitcnt lgkmcnt(0)" ::: "memory");
    __builtin_amdgcn_s_barrier();
    __builtin_amdgcn_sched_barrier(0);
    asm volatile("" ::: "memory");
  };

  // fbf biases -> LDS (once)
  for (int i = tid; i < HID*DIN; i += NTHREADS) fbfs[i] = fbf[i];

  // ---- init: z0 = coeffs[:,0,:] @ init_w.T + init_b ----
  if (tid < BT*DIN){
    int r = tid >> 5, d = tid & 31;
    actC[SWZ(r, d)] = (_Float16)coeffs[(b0 + r)*(L_T*DIN) + d];
  }
  bar();
  if (w < 8){
    f32x4 acc = {0.f,0.f,0.f,0.f};
    half8 a = *(const half8*)(actC + SWZ(cl, 8*g));
    half8 b = *(const half8*)(Wi + (w*64 + lane)*8);
    acc = __builtin_amdgcn_mfma_f32_16x16x32_f16(a, b, acc, 0, 0, 0);
    float bn = init_b[w*16 + cl];
#pragma unroll
    for (int r = 0; r < 4; ++r){
      float v = acc[r] + bn;
      zf[4*g + r][w*16 + cl] = v;
      actZ[SWZ(4*g + r, w*16 + cl)] = (_Float16)v;
    }
  }
  bar();

// Dense HID->HID layer; B-fragments loaded inline from L2-resident weights
// (4 independent 16B loads/wave; 8 waves/EU TLP hides latency).
#define DENSE(IN, OB, WT, BIAS) {                                          \
    f32x4 acc = {0.f,0.f,0.f,0.f};                                         \
    _Pragma("unroll")                                                      \
    for (int kq = 0; kq < 4; ++kq){                                        \
      half8 a = *(const half8*)((IN) + SWZ(cl, kq*32 + 8*g));              \
      half8 b = *(const half8*)((WT) + ((w*4 + kq)*64 + lane)*8);          \
      acc = __builtin_amdgcn_mfma_f32_16x16x32_f16(a, b, acc, 0,0,0);}     \
    float bn = (BIAS)[w*16 + cl];                                          \
    _Pragma("unroll")                                                      \
    for (int r = 0; r < 4; ++r)                                            \
      (OB)[SWZ(4*g + r, w*16 + cl)] = (_Float16)fast_tanh(acc[r] + bn); }

#define DECODER(TS) {                                                      \
    int dw = w - 14;                                                       \
    f32x4 acc = {0.f,0.f,0.f,0.f};                                         \
    _Pragma("unroll")                                                      \
    for (int kq = 0; kq < 4; ++kq){                                        \
      half8 a = *(const half8*)(actZ + SWZ(cl, kq*32 + 8*g));              \
      half8 b = *(const half8*)(Wd + ((dw*4 + kq)*64 + lane)*8);           \
      acc = __builtin_amdgcn_mfma_f32_16x16x32_f16(a, b, acc, 0,0,0);}     \
    float bn = dec_b[dw*16 + cl];                                          \
    _Pragma("unroll")                                                      \
    for (int r = 0; r < 4; ++r)                                            \
      out[(b0 + 4*g + r)*(L_T*DOUT) + (TS)*DOUT + dw*16 + cl] = acc[r] + bn; }

  float dxlo[4], dxhi[4];

  for (int t = 0; t < L_T - 1; ++t){
    // decoder(t) on waves 14/15: overlaps dxs setup + dense0 of this step.
    // Safe: its actZ ds_reads drain at this wave's bar() below, and actZ
    // is first rewritten at s=0's combine, 4 barriers later.
    if (w >= 14) DECODER(t)

    float dt = times[t+1] - times[t];
    if (tid < BT*DIN){
      int r = tid >> 5, d = tid & 31;
      const float* cp = coeffs + (b0 + r)*(L_T*DIN) + t*DIN + d;
      dxs[r][d] = (cp[DIN] - cp[0]) / dt;
    }
    bar();
#pragma unroll
    for (int r = 0; r < 4; ++r){
      dxlo[r] = dxs[4*g + r][cl];
      dxhi[r] = dxs[4*g + r][16 + cl];
    }

    for (int s = 0; s < 4; ++s){
      if (w < 8) DENSE(actZ, actB, W0, fb0)
      bar();
      if (w < 8) DENSE(actB, actC, W1, fb1)
      bar();
      if (w < 8) DENSE(actC, actB, W2, fb2)
      bar();

      // ---- biglayer: all 16 waves, 8 h-rows each, direct tile loads.
      // One tile buffer; d=0..15 half sets p, d=16..31 half accumulates,
      // keeping peak live regs ~60 (<= the 64-VGPR budget -> no spill).
      {
        half8 af[4];
#pragma unroll
        for (int kq = 0; kq < 4; ++kq)
          af[kq] = *(const half8*)(actB + SWZ(cl, kq*32 + 8*g));
        float p[4];
#pragma unroll
        for (int hh = 0; hh < 8; ++hh){
          {
            const _Float16* tp = Wfw + (2*hh)*2048 + lane*8;
            f32x4 acc = {0.f,0.f,0.f,0.f};
#pragma unroll
            for (int j = 0; j < 4; ++j)
              acc = __builtin_amdgcn_mfma_f32_16x16x32_f16(
                        af[j], *(const half8*)(tp + 512*j), acc, 0,0,0);
            float bn = fbfs[(w*16 + 2*hh)*16 + cl];
#pragma unroll
            for (int r = 0; r < 4; ++r)
              p[r] = fast_tanh(acc[r] + bn) * dxlo[r];
          }
          {
            const _Float16* tp = Wfw + (2*hh + 1)*2048 + lane*8;
            f32x4 acc = {0.f,0.f,0.f,0.f};
#pragma unroll
            for (int j = 0; j < 4; ++j)
              acc = __builtin_amdgcn_mfma_f32_16x16x32_f16(
                        af[j], *(const half8*)(tp + 512*j), acc, 0,0,0);
            float bn = fbfs[(w*16 + 2*hh + 1)*16 + cl];
#pragma unroll
            for (int r = 0; r < 4; ++r)
              p[r] += fast_tanh(acc[r] + bn) * dxhi[r];
          }
#pragma unroll
          for (int m = 1; m < 16; m <<= 1){
#pragma unroll
            for (int r = 0; r < 4; ++r) p[r] += __shfl_xor(p[r], m, 64);
          }
          if (cl == 0){
#pragma unroll
            for (int r = 0; r < 4; ++r) dzs[4*g + r][w*8 + hh] = p[r];
          }
        }
      }
      bar();

      // ---- RK4 combine (2048 elems, 2 per thread)
#pragma unroll
      for (int j = 0; j < 2; ++j){
        int e = tid + NTHREADS*j;
        int r = e >> 7, c = e & 127;
        float kv = dzs[r][c];
        float nin;
        if (s == 0){ kacc[r][c] = kv;            nin = zf[r][c] + 0.5f*dt*kv; }
        else if (s == 1){ kacc[r][c] += 2.0f*kv; nin = zf[r][c] + 0.5f*dt*kv; }
        else if (s == 2){ kacc[r][c] += 2.0f*kv; nin = zf[r][c] + dt*kv; }
        else {
          float zn = zf[r][c] + (dt * (1.0f/6.0f)) * (kacc[r][c] + kv);
          zf[r][c] = zn; nin = zn;
        }
        actZ[SWZ(r, c)] = (_Float16)nin;
      }
      bar();
    }
  }
  if (w >= 14) DECODER(L_T - 1)
}

extern "C" void kernel_launch(void* const* d_in, const int* in_sizes, int n_in,
                              void* d_out, int out_size, void* d_ws, size_t ws_size,
                              hipStream_t stream){
  const float* coeffs = (const float*)d_in[0];
  const float* times  = (const float*)d_in[1];
  const float* init_w = (const float*)d_in[2];
  const float* init_b = (const float*)d_in[3];
  const float* fw0    = (const float*)d_in[4];
  const float* fb0    = (const float*)d_in[5];
  const float* fw1    = (const float*)d_in[6];
  const float* fb1    = (const float*)d_in[7];
  const float* fw2    = (const float*)d_in[8];
  const float* fb2    = (const float*)d_in[9];
  const float* fwf    = (const float*)d_in[10];
  const float* fbf    = (const float*)d_in[11];
  const float* dec_w  = (const float*)d_in[12];
  const float* dec_b  = (const float*)d_in[13];
  _Float16* W = (_Float16*)d_ws;

  hipLaunchKernelGGL(reorder_w, dim3(64),   dim3(256), 0, stream, fw0, W,          128, 128);
  hipLaunchKernelGGL(reorder_w, dim3(64),   dim3(256), 0, stream, fw1, W + 16384,  128, 128);
  hipLaunchKernelGGL(reorder_w, dim3(64),   dim3(256), 0, stream, fw2, W + 32768,  128, 128);
  hipLaunchKernelGGL(reorder_w, dim3(2048), dim3(256), 0, stream, fwf, W + 49152,  4096, 128);
  hipLaunchKernelGGL(reorder_w, dim3(16),   dim3(256), 0, stream, init_w, W + 573440, 128, 32);
  hipLaunchKernelGGL(reorder_w, dim3(16),   dim3(256), 0, stream, dec_w,  W + 577536,  32, 128);

  hipLaunchKernelGGL(cde_main, dim3(NBLK), dim3(NTHREADS), 0, stream,
                     coeffs, times, init_b, fb0, fb1, fb2, fbf, dec_b,
                     W, (float*)d_out);
}